// Round 1
// baseline (59.245 us; speedup 1.0000x reference)
//
#include <hip/hip_runtime.h>
#include <hip/hip_bf16.h>

// GAT layer: out[b,i,j] = lrelu( (h@W@a1)[b,i] + (h@W@a2)[b,j] )
// B=4, N=4096, IN_F=256, OUT_F=64. Output: 4*4096*4096 fp32 = 256 MiB (write-bound).

#define B_DIM 4
#define N_DIM 4096
#define IN_F 256
#define OUT_F 64
#define SLOPE 0.2f

// Kernel 1: v1[k] = sum_j W[k][j]*a[j], v2[k] = sum_j W[k][j]*a[64+j].  One block, 256 threads.
__global__ void gat_compute_v(const float* __restrict__ W, const float* __restrict__ a,
                              float* __restrict__ v /* [512]: v1 then v2 */) {
    int k = threadIdx.x;  // 0..255
    float s1 = 0.f, s2 = 0.f;
    const float* wr = W + k * OUT_F;
    #pragma unroll 8
    for (int j = 0; j < OUT_F; ++j) {
        float w = wr[j];
        s1 += w * a[j];
        s2 += w * a[OUT_F + j];
    }
    v[k] = s1;
    v[IN_F + k] = s2;
}

// Kernel 2: one wave (64 lanes) per row; lane i loads float4 i of the 256-float row.
// e1[row] = h_row . v1 ; e2[row] = h_row . v2.  rows = B*N = 16384.
__global__ void gat_row_dots(const float* __restrict__ h, const float* __restrict__ v,
                             float* __restrict__ e1, float* __restrict__ e2) {
    int gid  = blockIdx.x * blockDim.x + threadIdx.x;
    int row  = gid >> 6;          // wave index
    int lane = threadIdx.x & 63;
    if (row >= B_DIM * N_DIM) return;

    const float4 hv = reinterpret_cast<const float4*>(h + (size_t)row * IN_F)[lane];
    const float4 v1 = reinterpret_cast<const float4*>(v)[lane];
    const float4 v2 = reinterpret_cast<const float4*>(v + IN_F)[lane];

    float d1 = hv.x * v1.x + hv.y * v1.y + hv.z * v1.z + hv.w * v1.w;
    float d2 = hv.x * v2.x + hv.y * v2.y + hv.z * v2.z + hv.w * v2.w;

    // 64-lane butterfly reduce
    #pragma unroll
    for (int m = 32; m >= 1; m >>= 1) {
        d1 += __shfl_xor(d1, m);
        d2 += __shfl_xor(d2, m);
    }
    if (lane == 0) {
        e1[row] = d1;
        e2[row] = d2;
    }
}

// Kernel 3: epilogue — out[b,i,j] = fmaxf(e, SLOPE*e), e = e1[b*N+i] + e2[b*N+j].
// float4 stores; e2 row (16 KB per batch) stays L2-resident.
__global__ void gat_epilogue(const float* __restrict__ e1, const float* __restrict__ e2,
                             float* __restrict__ out) {
    const int total4 = B_DIM * N_DIM * (N_DIM / 4);   // 16,777,216 float4
    const int stride = gridDim.x * blockDim.x;
    const float4* e2v = reinterpret_cast<const float4*>(e2);
    float4* outv = reinterpret_cast<float4*>(out);

    for (int idx = blockIdx.x * blockDim.x + threadIdx.x; idx < total4; idx += stride) {
        int row = idx >> 10;           // b*N + i   (N/4 = 1024 float4 per row)
        int c4  = idx & 1023;
        int b   = row >> 12;           // row / 4096
        float s = e1[row];
        float4 t = e2v[b * (N_DIM / 4) + c4];
        float4 o;
        float ex = s + t.x; o.x = fmaxf(ex, SLOPE * ex);
        float ey = s + t.y; o.y = fmaxf(ey, SLOPE * ey);
        float ez = s + t.z; o.z = fmaxf(ez, SLOPE * ez);
        float ew = s + t.w; o.w = fmaxf(ew, SLOPE * ew);
        outv[idx] = o;
    }
}

extern "C" void kernel_launch(void* const* d_in, const int* in_sizes, int n_in,
                              void* d_out, int out_size, void* d_ws, size_t ws_size,
                              hipStream_t stream) {
    const float* h = (const float*)d_in[0];   // 4*4096*256
    const float* W = (const float*)d_in[1];   // 256*64
    const float* a = (const float*)d_in[2];   // 128

    float* ws = (float*)d_ws;
    float* v  = ws;                    // 512 floats
    float* e1 = ws + 512;              // 16384 floats
    float* e2 = ws + 512 + 16384;      // 16384 floats

    gat_compute_v<<<1, 256, 0, stream>>>(W, a, v);

    const int rows = B_DIM * N_DIM;                 // 16384 waves
    gat_row_dots<<<rows * 64 / 256, 256, 0, stream>>>(h, v, e1, e2);

    gat_epilogue<<<2048, 256, 0, stream>>>(e1, e2, (float*)d_out);
}